// Round 1
// baseline (26677.322 us; speedup 1.0000x reference)
//
#include <hip/hip_runtime.h>

#define TL 2048

typedef __attribute__((ext_vector_type(8))) short bfx8;
typedef __attribute__((ext_vector_type(4))) float fx4;

__device__ __forceinline__ float sigf(float x){ return __builtin_amdgcn_rcpf(1.0f + __expf(-x)); }
__device__ __forceinline__ float tanhff(float x){ return fmaf(2.0f, sigf(2.0f*x), -1.0f); }

template<int CTRL>
__device__ __forceinline__ float dpp_xadd(float v){
  int s = __builtin_amdgcn_update_dpp(0, __float_as_int(v), CTRL, 0xF, 0xF, true);
  return v + __int_as_float(s);
}
__device__ __forceinline__ float swz4_add(float v){
  int s = __builtin_amdgcn_ds_swizzle(__float_as_int(v), 0x101F);
  return v + __int_as_float(s);
}
__device__ __forceinline__ float bperm(float v, int srclane){
  return __int_as_float(__builtin_amdgcn_ds_bpermute(srclane << 2, __float_as_int(v)));
}
__device__ __forceinline__ unsigned short f2bf(float f){   // RNE fp32->bf16
  unsigned int u = __float_as_uint(f);
  u += 0x7fffu + ((u >> 16) & 1u);
  return (unsigned short)(u >> 16);
}
__device__ __forceinline__ float dot4(float4 a, float4 b, float acc){
  acc = fmaf(a.x, b.x, acc); acc = fmaf(a.y, b.y, acc);
  acc = fmaf(a.z, b.z, acc); acc = fmaf(a.w, b.w, acc);
  return acc;
}
// LDS-only barrier: do NOT drain vmcnt (global h-stores stay in flight).
__device__ __forceinline__ void barrier_lgkm(){
  asm volatile("s_waitcnt lgkmcnt(0)\ns_barrier" ::: "memory");
}
__device__ __forceinline__ bfx8 pack8(const float* p){
  bfx8 r;
  #pragma unroll
  for (int i = 0; i < 8; ++i) r[i] = (short)f2bf(p[i]);
  return r;
}

// Uber-kernel; segments selected per-block by [nL1 | nL2 | nL3]:
//   blockIdx [0,nL1)            : L1 scan (fp32 VALU, D=2 folded), h1 out bf16
//   blockIdx [nL1,nL1+nL2)      : L2 scan, Wih2 proj via MFMA 16-step lookahead
//   blockIdx [nL1+nL2, +nL3)    : L3 scan, Wih3 proj via MFMA + T-mean accumulate
// __launch_bounds__(512,4): 4 waves/EU -> 2 blocks/CU co-resident (VGPR cap 128;
// measured 120). Needed so full-width 512-WG dispatches double-occupy each CU and
// the second chain's VALU issue fills the ~43% latency stall of the first.
__global__ __launch_bounds__(512, 4) void mega_kernel(
    int nL1, int nL2, int nL3, int cb1, int cb2, int cb3, int p1, int p2, int p3,
    const float* __restrict__ x,
    const float* __restrict__ Wih1, const float* __restrict__ Whh1,
    const float* __restrict__ bih1, const float* __restrict__ bhh1,
    const float* __restrict__ Wih2, const float* __restrict__ Whh2,
    const float* __restrict__ bih2, const float* __restrict__ bhh2,
    const float* __restrict__ Wih3, const float* __restrict__ Whh3,
    const float* __restrict__ bih3, const float* __restrict__ bhh3,
    unsigned short* __restrict__ h1r0, unsigned short* __restrict__ h1r1,
    unsigned short* __restrict__ o2r0, unsigned short* __restrict__ o2r1,
    float* __restrict__ sums)
{
  __shared__ __align__(16) unsigned char smem[34816];
  const int tid  = threadIdx.x;
  const int bid  = blockIdx.x;
  const int lane = tid & 63;
  const int wv   = tid >> 6;

  if (bid < nL1){
    // ================= L1: H=128, D=2 folded. WG = one (b,dir) chain. ======
    const int bloc = bid >> 1, dir = bid & 1;
    unsigned short* h1o = p1 ? h1r1 : h1r0;
    const int kc = tid & 3, u = tid >> 2;

    float4 w[4][8];
    const float* Wh = Whh1 + dir * 65536;
    #pragma unroll
    for (int g = 0; g < 4; ++g){
      const float* row = Wh + (g * 128 + u) * 128 + kc * 32;
      #pragma unroll
      for (int q = 0; q < 8; ++q){
        const int ro = (q + 2 * kc) & 7;
        w[g][q] = *(const float4*)(row + ro * 4);
      }
    }
    float xwA[4], xwB[4], bs[4];
    #pragma unroll
    for (int g = 0; g < 4; ++g){
      const int r = g * 128 + u;
      xwA[g] = Wih1[dir * 1024 + r * 2];
      xwB[g] = Wih1[dir * 1024 + r * 2 + 1];
      bs[g]  = bih1[dir * 512 + r] + bhh1[dir * 512 + r];
    }
    float* xlds = (float*)smem;                  // 4096 f (full x row)
    float* hbuf = (float*)(smem + 16384);        // 2 x 128 f
    {
      const float* xb = x + (size_t)(cb1 + bloc) * (TL * 2);
      for (int idx = tid; idx < TL * 2; idx += 512) xlds[idx] = xb[idx];
    }
    if (tid < 128){ hbuf[tid] = 0.0f; hbuf[128 + tid] = 0.0f; }
    __syncthreads();

    float cst = 0.0f;
    for (int t = 0; t < TL; ++t){
      const int tt  = dir ? (TL - 1 - t) : t;
      const int cur = t & 1;
      const float4* hp = (const float4*)(hbuf + cur * 128) + kc * 8;
      float a0 = 0.f, a1 = 0.f, a2 = 0.f, a3 = 0.f;
      #pragma unroll
      for (int q = 0; q < 8; ++q){
        const float4 hv = hp[(q + 2 * kc) & 7];
        a0 = dot4(w[0][q], hv, a0);
        a1 = dot4(w[1][q], hv, a1);
        a2 = dot4(w[2][q], hv, a2);
        a3 = dot4(w[3][q], hv, a3);
      }
      a0 = dpp_xadd<0x4E>(dpp_xadd<0xB1>(a0));
      a1 = dpp_xadd<0x4E>(dpp_xadd<0xB1>(a1));
      a2 = dpp_xadd<0x4E>(dpp_xadd<0xB1>(a2));
      a3 = dpp_xadd<0x4E>(dpp_xadd<0xB1>(a3));
      if (kc == 0){
        const float x0 = xlds[tt * 2], x1 = xlds[tt * 2 + 1];
        const float p0 = a0 + fmaf(xwA[0], x0, fmaf(xwB[0], x1, bs[0]));
        const float p1 = a1 + fmaf(xwA[1], x0, fmaf(xwB[1], x1, bs[1]));
        const float p2 = a2 + fmaf(xwA[2], x0, fmaf(xwB[2], x1, bs[2]));
        const float p3 = a3 + fmaf(xwA[3], x0, fmaf(xwB[3], x1, bs[3]));
        const float ig = sigf(p0), fg = sigf(p1), gg = tanhff(p2), og = sigf(p3);
        cst = fmaf(fg, cst, ig * gg);
        const float h = og * tanhff(cst);
        hbuf[(cur ^ 1) * 128 + u] = h;
        h1o[((size_t)bloc * TL + tt) * 256 + dir * 128 + u] = f2bf(h);
      }
      barrier_lgkm();
    }

  } else if (bid < nL1 + nL2){
    // ================= L2: H=64; proj (K=256) via MFMA lookahead. ==========
    const int i2 = bid - nL1;
    const int bloc = i2 >> 1, dir = i2 & 1;
    const unsigned short* h1i = (p2 ? h1r1 : h1r0) + (size_t)bloc * TL * 256;
    unsigned short* o2o = p2 ? o2r1 : o2r0;
    const int kc = tid & 7, u = tid >> 3;

    // recurrence weights fp32 (K=64 split kc*8) + bias
    float4 wr[4][2]; float bs[4];
    const float* WR = Whh2 + dir * 16384;
    #pragma unroll
    for (int tgt = 0; tgt < 4; ++tgt){
      const int row = tgt * 64 + u;
      wr[tgt][0] = *(const float4*)(WR + row * 64 + kc * 8);
      wr[tgt][1] = *(const float4*)(WR + row * 64 + kc * 8 + 4);
      bs[tgt] = bih2[dir * 256 + row] + bhh2[dir * 256 + row];
    }
    // MFMA B-frags: wave wv owns gate tiles {2wv, 2wv+1}; B[n][k] = Wih2[n][k]
    bfx8 Bf[2][8];
    const float* WP = Wih2 + dir * 65536;
    #pragma unroll
    for (int ntl = 0; ntl < 2; ++ntl){
      const int n = (2 * wv + ntl) * 16 + (lane & 15);
      #pragma unroll
      for (int Kf = 0; Kf < 8; ++Kf)
        Bf[ntl][Kf] = pack8(WP + n * 256 + Kf * 32 + (lane >> 4) * 8);
    }
    float* xs  = (float*)smem;                   // 2 bufs x 16 x 258 f
    float* h2b = (float*)(smem + 33024);         // 2 x 64 f
    if (tid < 64){ h2b[tid] = 0.0f; h2b[64 + tid] = 0.0f; }

    auto loadA = [&](int blk, uint4* a8){
      const int m  = lane & 15;
      const int pt = dir ? (TL - 1 - (blk * 16 + m)) : (blk * 16 + m);
      const unsigned short* base = h1i + (size_t)pt * 256 + (lane >> 4) * 8;
      #pragma unroll
      for (int Kf = 0; Kf < 8; ++Kf) a8[Kf] = *(const uint4*)(base + Kf * 32);
    };
    auto domfma = [&](uint4* a8, int buf){
      fx4 acc0 = {0.f,0.f,0.f,0.f}, acc1 = {0.f,0.f,0.f,0.f};
      #pragma unroll
      for (int Kf = 0; Kf < 8; ++Kf){
        bfx8 av; __builtin_memcpy(&av, &a8[Kf], 16);
        acc0 = __builtin_amdgcn_mfma_f32_16x16x32_bf16(av, Bf[0][Kf], acc0, 0, 0, 0);
        acc1 = __builtin_amdgcn_mfma_f32_16x16x32_bf16(av, Bf[1][Kf], acc1, 0, 0, 0);
      }
      const int c0 = (2 * wv) * 16 + (lane & 15);
      #pragma unroll
      for (int rr = 0; rr < 4; ++rr){
        const int row = (lane >> 4) * 4 + rr;
        xs[buf * 4128 + row * 258 + c0]      = acc0[rr];
        xs[buf * 4128 + row * 258 + c0 + 16] = acc1[rr];
      }
    };

    uint4 a8[8];
    loadA(0, a8); domfma(a8, 0);
    loadA(1, a8); domfma(a8, 1);
    __syncthreads();

    float cst = 0.0f;
    uint4 pf[8];
    for (int B = 0; B < 128; ++B){
      if (B + 2 < 128) loadA(B + 2, pf);      // issue; consumed after the 16 steps
      const int pb = B & 1;
      for (int s = 0; s < 16; ++s){
        const int t  = B * 16 + s;
        const int tt = dir ? (TL - 1 - t) : t;
        const int cur = t & 1;
        const float4* hv4 = (const float4*)(h2b + cur * 64) + kc * 2;
        const float4 hA = hv4[0], hB = hv4[1];
        float a0 = dot4(wr[0][1], hB, dot4(wr[0][0], hA, 0.f));
        float a1 = dot4(wr[1][1], hB, dot4(wr[1][0], hA, 0.f));
        float a2 = dot4(wr[2][1], hB, dot4(wr[2][0], hA, 0.f));
        float a3 = dot4(wr[3][1], hB, dot4(wr[3][0], hA, 0.f));
        a0 = swz4_add(dpp_xadd<0x4E>(dpp_xadd<0xB1>(a0)));
        a1 = swz4_add(dpp_xadd<0x4E>(dpp_xadd<0xB1>(a1)));
        a2 = swz4_add(dpp_xadd<0x4E>(dpp_xadd<0xB1>(a2)));
        a3 = swz4_add(dpp_xadd<0x4E>(dpp_xadd<0xB1>(a3)));
        if (kc == 0){
          const float* xr = xs + pb * 4128 + s * 258 + u;
          const float ig = sigf(a0 + xr[0]   + bs[0]);
          const float fg = sigf(a1 + xr[64]  + bs[1]);
          const float gg = tanhff(a2 + xr[128] + bs[2]);
          const float og = sigf(a3 + xr[192] + bs[3]);
          cst = fmaf(fg, cst, ig * gg);
          const float h = og * tanhff(cst);
          h2b[(cur ^ 1) * 64 + u] = h;
          o2o[((size_t)bloc * TL + tt) * 128 + dir * 64 + u] = f2bf(h);
        }
        barrier_lgkm();
      }
      if (B + 2 < 128) domfma(pf, pb);        // fills buf pb for block B+2
    }

  } else {
    // ================= L3: H=16; proj (K=128) via MFMA; T-mean in regs. ====
    // WG = 4 chains (same dir). 2 waves per chain.
    const int i3 = bid - nL1 - nL2;
    const int dir = i3 & 1, q4 = i3 >> 1;
    const int grp = tid >> 7, lt = tid & 127;
    const int bloc = q4 * 4 + grp;
    const unsigned short* o2i = (p3 ? o2r1 : o2r0) + (size_t)bloc * TL * 128;
    const int u = lt >> 3, j = lt & 7, gt = j >> 1, kc = j & 1;
    const int half = wv & 1;

    const float* WR = Whh3 + dir * 1024;
    const int r = gt * 16 + u;
    const float4 wr0 = *(const float4*)(WR + r * 16 + kc * 8);
    const float4 wr1 = *(const float4*)(WR + r * 16 + kc * 8 + 4);
    const float bsv = bih3[dir * 64 + r] + bhh3[dir * 64 + r];
    const int ubase = lane & ~7;
    const float bI = bperm(bsv, ubase + 0), bF = bperm(bsv, ubase + 2);
    const float bG = bperm(bsv, ubase + 4), bO = bperm(bsv, ubase + 6);

    bfx8 Bf[2][4];
    const float* WP = Wih3 + dir * 8192;     // (64,128)
    #pragma unroll
    for (int ntl = 0; ntl < 2; ++ntl){
      const int n = (2 * half + ntl) * 16 + (lane & 15);
      #pragma unroll
      for (int Kf = 0; Kf < 4; ++Kf)
        Bf[ntl][Kf] = pack8(WP + n * 128 + Kf * 32 + (lane >> 4) * 8);
    }
    float* xs  = (float*)smem + grp * 2112;  // per chain: 2 bufs x 16 x 66 f
    float* h3b = (float*)(smem + 33792) + grp * 32;
    if (lt < 32) h3b[lt] = 0.0f;

    auto loadA3 = [&](int blk, uint4* a4){
      const int m  = lane & 15;
      const int pt = dir ? (TL - 1 - (blk * 16 + m)) : (blk * 16 + m);
      const unsigned short* base = o2i + (size_t)pt * 128 + (lane >> 4) * 8;
      #pragma unroll
      for (int Kf = 0; Kf < 4; ++Kf) a4[Kf] = *(const uint4*)(base + Kf * 32);
    };
    auto domfma3 = [&](uint4* a4, int buf){
      fx4 acc0 = {0.f,0.f,0.f,0.f}, acc1 = {0.f,0.f,0.f,0.f};
      #pragma unroll
      for (int Kf = 0; Kf < 4; ++Kf){
        bfx8 av; __builtin_memcpy(&av, &a4[Kf], 16);
        acc0 = __builtin_amdgcn_mfma_f32_16x16x32_bf16(av, Bf[0][Kf], acc0, 0, 0, 0);
        acc1 = __builtin_amdgcn_mfma_f32_16x16x32_bf16(av, Bf[1][Kf], acc1, 0, 0, 0);
      }
      const int c0 = (2 * half) * 16 + (lane & 15);
      #pragma unroll
      for (int rr = 0; rr < 4; ++rr){
        const int row = (lane >> 4) * 4 + rr;
        xs[buf * 1056 + row * 66 + c0]      = acc0[rr];
        xs[buf * 1056 + row * 66 + c0 + 16] = acc1[rr];
      }
    };

    uint4 a4[4];
    loadA3(0, a4); domfma3(a4, 0);
    loadA3(1, a4); domfma3(a4, 1);
    __syncthreads();

    float cst = 0.0f, msum = 0.0f;
    uint4 pf[4];
    for (int B = 0; B < 128; ++B){
      if (B + 2 < 128) loadA3(B + 2, pf);
      const int pb = B & 1;
      for (int s = 0; s < 16; ++s){
        const int t = B * 16 + s;
        const int cur = t & 1;
        const float4* h3p = (const float4*)(h3b + cur * 16 + kc * 8);
        float acc = dot4(wr1, h3p[1], dot4(wr0, h3p[0], 0.f));
        acc = dpp_xadd<0xB1>(acc);
        const float gI = bperm(acc, ubase + 0), gF = bperm(acc, ubase + 2);
        const float gG = bperm(acc, ubase + 4), gO = bperm(acc, ubase + 6);
        if (j == 0){
          const float* xr = xs + pb * 1056 + s * 66 + u;
          const float ig = sigf(gI + bI + xr[0]);
          const float fg = sigf(gF + bF + xr[16]);
          const float gg = tanhff(gG + bG + xr[32]);
          const float og = sigf(gO + bO + xr[48]);
          cst = fmaf(fg, cst, ig * gg);
          const float h = og * tanhff(cst);
          h3b[(cur ^ 1) * 16 + u] = h;
          msum += h;
        }
        barrier_lgkm();
      }
      if (B + 2 < 128) domfma3(pf, pb);
    }
    if (j == 0) sums[(size_t)(cb3 + bloc) * 32 + dir * 16 + u] = msum;
  }
}

// ---------------- head: mean (pre-summed) + MLP, one 64-thr WG per batch
__global__ __launch_bounds__(64) void head_kernel(
    const float* __restrict__ sums,
    const float* __restrict__ hW1, const float* __restrict__ hb1,
    const float* __restrict__ hW2, const float* __restrict__ hb2,
    const float* __restrict__ hW3, const float* __restrict__ hb3,
    float* __restrict__ out)
{
  __shared__ float m[32], h1s[64], h2s[16];
  const int tid = threadIdx.x, b = blockIdx.x;
  if (tid < 32) m[tid] = sums[b * 32 + tid] * (1.0f / 2048.0f);
  __syncthreads();
  {
    float a = hb1[tid];
    #pragma unroll
    for (int k = 0; k < 32; ++k) a = fmaf(m[k], hW1[tid * 32 + k], a);
    h1s[tid] = fmaxf(a, 0.0f);
  }
  __syncthreads();
  if (tid < 16){
    float a = hb2[tid];
    #pragma unroll
    for (int k = 0; k < 64; ++k) a = fmaf(h1s[k], hW2[tid * 64 + k], a);
    h2s[tid] = fmaxf(a, 0.0f);
  }
  __syncthreads();
  if (tid < 20){
    float a = hb3[tid];
    #pragma unroll
    for (int k = 0; k < 16; ++k) a = fmaf(h2s[k], hW3[tid * 16 + k], a);
    out[b * 20 + tid] = a;
  }
}

extern "C" void kernel_launch(void* const* d_in, const int* in_sizes, int n_in,
                              void* d_out, int out_size, void* d_ws, size_t ws_size,
                              hipStream_t stream) {
  (void)in_sizes; (void)n_in; (void)out_size;
  const float* x    = (const float*)d_in[0];
  const float* Wih1 = (const float*)d_in[1];
  const float* Whh1 = (const float*)d_in[2];
  const float* bih1 = (const float*)d_in[3];
  const float* bhh1 = (const float*)d_in[4];
  const float* Wih2 = (const float*)d_in[5];
  const float* Whh2 = (const float*)d_in[6];
  const float* bih2 = (const float*)d_in[7];
  const float* bhh2 = (const float*)d_in[8];
  const float* Wih3 = (const float*)d_in[9];
  const float* Whh3 = (const float*)d_in[10];
  const float* bih3 = (const float*)d_in[11];
  const float* bhh3 = (const float*)d_in[12];
  const float* hW1  = (const float*)d_in[13];
  const float* hb1  = (const float*)d_in[14];
  const float* hW2  = (const float*)d_in[15];
  const float* hb2  = (const float*)d_in[16];
  const float* hW3  = (const float*)d_in[17];
  const float* hb3  = (const float*)d_in[18];
  unsigned char* ws = (unsigned char*)d_ws;

  if (ws_size >= 402685952ull) {
    // ===== Tier 1: fully serialized, full-width stages, 2 blocks/CU. =====
    // h1 (256,2048,256) bf16 = 268,435,456 B | o2 (256,2048,128) bf16 =
    // 134,217,728 B | sums (256,32) f32 = 32,768 B. Total 402,685,952 B.
    unsigned short* h1 = (unsigned short*)ws;
    unsigned short* o2 = (unsigned short*)(ws + 268435456u);
    float* sums = (float*)(ws + 402653184u);
    mega_kernel<<<dim3(512), dim3(512), 0, stream>>>(   // L1: all 512 chains
        512, 0, 0, 0, 0, 0, 0, 0, 0,
        x, Wih1, Whh1, bih1, bhh1, Wih2, Whh2, bih2, bhh2,
        Wih3, Whh3, bih3, bhh3, h1, h1, o2, o2, sums);
    mega_kernel<<<dim3(512), dim3(512), 0, stream>>>(   // L2: all 512 chains
        0, 512, 0, 0, 0, 0, 0, 0, 0,
        x, Wih1, Whh1, bih1, bhh1, Wih2, Whh2, bih2, bhh2,
        Wih3, Whh3, bih3, bhh3, h1, h1, o2, o2, sums);
    mega_kernel<<<dim3(128), dim3(512), 0, stream>>>(   // L3: 4 chains/WG
        0, 0, 128, 0, 0, 0, 0, 0, 0,
        x, Wih1, Whh1, bih1, bhh1, Wih2, Whh2, bih2, bhh2,
        Wih3, Whh3, bih3, bhh3, h1, h1, o2, o2, sums);
    head_kernel<<<dim3(256), dim3(64), 0, stream>>>(
        sums, hW1, hb1, hW2, hb2, hW3, hb3, (float*)d_out);
    return;
  }

  if (ws_size >= 335577088ull) {
    // ===== Tier 2: full-width L1, then L2/L3 in half-B passes reusing one
    // 64 MiB o2 half-buffer. h1 268,435,456 | o2half 67,108,864 | sums.
    unsigned short* h1   = (unsigned short*)ws;
    unsigned short* h1hi = h1 + (size_t)128 * TL * 256;   // batches 128..255
    unsigned short* o2   = (unsigned short*)(ws + 268435456u);
    float* sums = (float*)(ws + 335544320u);
    mega_kernel<<<dim3(512), dim3(512), 0, stream>>>(   // L1: all
        512, 0, 0, 0, 0, 0, 0, 0, 0,
        x, Wih1, Whh1, bih1, bhh1, Wih2, Whh2, bih2, bhh2,
        Wih3, Whh3, bih3, bhh3, h1, h1, o2, o2, sums);
    mega_kernel<<<dim3(256), dim3(512), 0, stream>>>(   // L2: b 0..127
        0, 256, 0, 0, 0, 0, 0, 0, 0,
        x, Wih1, Whh1, bih1, bhh1, Wih2, Whh2, bih2, bhh2,
        Wih3, Whh3, bih3, bhh3, h1, h1, o2, o2, sums);
    mega_kernel<<<dim3(64), dim3(512), 0, stream>>>(    // L3: b 0..127
        0, 0, 64, 0, 0, 0, 0, 0, 0,
        x, Wih1, Whh1, bih1, bhh1, Wih2, Whh2, bih2, bhh2,
        Wih3, Whh3, bih3, bhh3, h1, h1, o2, o2, sums);
    mega_kernel<<<dim3(256), dim3(512), 0, stream>>>(   // L2: b 128..255
        0, 256, 0, 0, 0, 0, 0, 0, 0,
        x, Wih1, Whh1, bih1, bhh1, Wih2, Whh2, bih2, bhh2,
        Wih3, Whh3, bih3, bhh3, h1hi, h1hi, o2, o2, sums);
    mega_kernel<<<dim3(64), dim3(512), 0, stream>>>(    // L3: b 128..255
        0, 0, 64, 0, 0, 128, 0, 0, 0,
        x, Wih1, Whh1, bih1, bhh1, Wih2, Whh2, bih2, bhh2,
        Wih3, Whh3, bih3, bhh3, h1, h1, o2, o2, sums);
    head_kernel<<<dim3(256), dim3(64), 0, stream>>>(
        sums, hW1, hb1, hW2, hb2, hW3, hb3, (float*)d_out);
    return;
  }

  // ===== Tier 3: pipelined fallback, chunks {52,52,52,52,48} (was 6x48).
  // One fewer L1-bearing dispatch. Rings: h1 2x 54,525,952 | o2 2x 27,262,976
  // | sums. Total 163,610,624 B <= 167.8 MB proven available.
  {
    unsigned short* h1r0 = (unsigned short*)ws;
    unsigned short* h1r1 = h1r0 + (size_t)52 * TL * 256;
    unsigned short* o2r0 = (unsigned short*)(ws + 109051904u);
    unsigned short* o2r1 = o2r0 + (size_t)52 * TL * 128;
    float* sums = (float*)(ws + 163577856u);

    const int cs[5] = {52, 52, 52, 52, 48};
    const int co[5] = {0, 52, 104, 156, 208};
    for (int k = 0; k < 7; ++k){
      const int a1 = (k < 5) ? cs[k] : 0;
      const int a2 = (k >= 1 && k < 6) ? cs[k - 1] : 0;
      const int a3 = (k >= 2) ? cs[k - 2] : 0;
      const int nL1 = 2 * a1, nL2 = 2 * a2, nL3 = a3 / 2;
      mega_kernel<<<dim3(nL1 + nL2 + nL3), dim3(512), 0, stream>>>(
          nL1, nL2, nL3,
          (k < 5) ? co[k] : 0, (k >= 1 && k < 6) ? co[k - 1] : 0,
          (k >= 2) ? co[k - 2] : 0,
          k & 1, (k + 1) & 1, k & 1,
          x, Wih1, Whh1, bih1, bhh1, Wih2, Whh2, bih2, bhh2,
          Wih3, Whh3, bih3, bhh3, h1r0, h1r1, o2r0, o2r1, sums);
    }
    head_kernel<<<dim3(256), dim3(64), 0, stream>>>(
        sums, hW1, hb1, hW2, hb2, hW3, hb3, (float*)d_out);
  }
}

// Round 2
// 8665.426 us; speedup vs baseline: 3.0786x; 3.0786x over previous
//
#include <hip/hip_runtime.h>

#define TL 2048

typedef __attribute__((ext_vector_type(8))) short bfx8;
typedef __attribute__((ext_vector_type(4))) float fx4;

__device__ __forceinline__ float sigf(float x){ return __builtin_amdgcn_rcpf(1.0f + __expf(-x)); }
__device__ __forceinline__ float tanhff(float x){ return fmaf(2.0f, sigf(2.0f*x), -1.0f); }

template<int CTRL>
__device__ __forceinline__ float dpp_xadd(float v){
  int s = __builtin_amdgcn_update_dpp(0, __float_as_int(v), CTRL, 0xF, 0xF, true);
  return v + __int_as_float(s);
}
__device__ __forceinline__ float swz4_add(float v){
  int s = __builtin_amdgcn_ds_swizzle(__float_as_int(v), 0x101F);
  return v + __int_as_float(s);
}
__device__ __forceinline__ float bperm(float v, int srclane){
  return __int_as_float(__builtin_amdgcn_ds_bpermute(srclane << 2, __float_as_int(v)));
}
__device__ __forceinline__ unsigned short f2bf(float f){   // RNE fp32->bf16
  unsigned int u = __float_as_uint(f);
  u += 0x7fffu + ((u >> 16) & 1u);
  return (unsigned short)(u >> 16);
}
__device__ __forceinline__ float dot4(float4 a, float4 b, float acc){
  acc = fmaf(a.x, b.x, acc); acc = fmaf(a.y, b.y, acc);
  acc = fmaf(a.z, b.z, acc); acc = fmaf(a.w, b.w, acc);
  return acc;
}
// LDS-only barrier: do NOT drain vmcnt (global h-stores stay in flight).
__device__ __forceinline__ void barrier_lgkm(){
  asm volatile("s_waitcnt lgkmcnt(0)\ns_barrier" ::: "memory");
}
__device__ __forceinline__ bfx8 pack8(const float* p){
  bfx8 r;
  #pragma unroll
  for (int i = 0; i < 8; ++i) r[i] = (short)f2bf(p[i]);
  return r;
}

// Uber-kernel; segments selected per-block by [nL1 | nL2 | nL3]:
//   blockIdx [0,nL1)            : L1 scan (fp32 VALU, D=2 folded), h1 out bf16
//   blockIdx [nL1,nL1+nL2)      : L2 scan, Wih2 proj via MFMA 16-step lookahead
//   blockIdx [nL1+nL2, +nL3)    : L3 scan, Wih3 proj via MFMA + T-mean accumulate
// __launch_bounds__(512,2): DO NOT raise the min-waves arg. (512,4) caps the
// allocator at 64 VGPR (round-1 regression: spill, 45 ms L1 dispatch). At
// (512,2) the compiler settles at 120 VGPR, which ALREADY admits 4 waves/EU
// (m69 occupancy steps: <=128 VGPR -> 4 waves/SIMD) = 2 blocks/CU co-resident
// on full-width 512-block grids, with zero spill.
__global__ __launch_bounds__(512, 2) void mega_kernel(
    int nL1, int nL2, int nL3, int cb1, int cb2, int cb3, int p1, int p2, int p3,
    const float* __restrict__ x,
    const float* __restrict__ Wih1, const float* __restrict__ Whh1,
    const float* __restrict__ bih1, const float* __restrict__ bhh1,
    const float* __restrict__ Wih2, const float* __restrict__ Whh2,
    const float* __restrict__ bih2, const float* __restrict__ bhh2,
    const float* __restrict__ Wih3, const float* __restrict__ Whh3,
    const float* __restrict__ bih3, const float* __restrict__ bhh3,
    unsigned short* __restrict__ h1r0, unsigned short* __restrict__ h1r1,
    unsigned short* __restrict__ o2r0, unsigned short* __restrict__ o2r1,
    float* __restrict__ sums)
{
  __shared__ __align__(16) unsigned char smem[34816];
  const int tid  = threadIdx.x;
  const int bid  = blockIdx.x;
  const int lane = tid & 63;
  const int wv   = tid >> 6;

  if (bid < nL1){
    // ================= L1: H=128, D=2 folded. WG = one (b,dir) chain. ======
    const int bloc = bid >> 1, dir = bid & 1;
    unsigned short* h1o = p1 ? h1r1 : h1r0;
    const int kc = tid & 3, u = tid >> 2;

    float4 w[4][8];
    const float* Wh = Whh1 + dir * 65536;
    #pragma unroll
    for (int g = 0; g < 4; ++g){
      const float* row = Wh + (g * 128 + u) * 128 + kc * 32;
      #pragma unroll
      for (int q = 0; q < 8; ++q){
        const int ro = (q + 2 * kc) & 7;
        w[g][q] = *(const float4*)(row + ro * 4);
      }
    }
    float xwA[4], xwB[4], bs[4];
    #pragma unroll
    for (int g = 0; g < 4; ++g){
      const int r = g * 128 + u;
      xwA[g] = Wih1[dir * 1024 + r * 2];
      xwB[g] = Wih1[dir * 1024 + r * 2 + 1];
      bs[g]  = bih1[dir * 512 + r] + bhh1[dir * 512 + r];
    }
    float* xlds = (float*)smem;                  // 4096 f (full x row)
    float* hbuf = (float*)(smem + 16384);        // 2 x 128 f
    {
      const float* xb = x + (size_t)(cb1 + bloc) * (TL * 2);
      for (int idx = tid; idx < TL * 2; idx += 512) xlds[idx] = xb[idx];
    }
    if (tid < 128){ hbuf[tid] = 0.0f; hbuf[128 + tid] = 0.0f; }
    __syncthreads();

    float cst = 0.0f;
    for (int t = 0; t < TL; ++t){
      const int tt  = dir ? (TL - 1 - t) : t;
      const int cur = t & 1;
      const float4* hp = (const float4*)(hbuf + cur * 128) + kc * 8;
      float a0 = 0.f, a1 = 0.f, a2 = 0.f, a3 = 0.f;
      #pragma unroll
      for (int q = 0; q < 8; ++q){
        const float4 hv = hp[(q + 2 * kc) & 7];
        a0 = dot4(w[0][q], hv, a0);
        a1 = dot4(w[1][q], hv, a1);
        a2 = dot4(w[2][q], hv, a2);
        a3 = dot4(w[3][q], hv, a3);
      }
      a0 = dpp_xadd<0x4E>(dpp_xadd<0xB1>(a0));
      a1 = dpp_xadd<0x4E>(dpp_xadd<0xB1>(a1));
      a2 = dpp_xadd<0x4E>(dpp_xadd<0xB1>(a2));
      a3 = dpp_xadd<0x4E>(dpp_xadd<0xB1>(a3));
      if (kc == 0){
        const float x0 = xlds[tt * 2], x1 = xlds[tt * 2 + 1];
        const float p0 = a0 + fmaf(xwA[0], x0, fmaf(xwB[0], x1, bs[0]));
        const float p1 = a1 + fmaf(xwA[1], x0, fmaf(xwB[1], x1, bs[1]));
        const float p2 = a2 + fmaf(xwA[2], x0, fmaf(xwB[2], x1, bs[2]));
        const float p3 = a3 + fmaf(xwA[3], x0, fmaf(xwB[3], x1, bs[3]));
        const float ig = sigf(p0), fg = sigf(p1), gg = tanhff(p2), og = sigf(p3);
        cst = fmaf(fg, cst, ig * gg);
        const float h = og * tanhff(cst);
        hbuf[(cur ^ 1) * 128 + u] = h;
        h1o[((size_t)bloc * TL + tt) * 256 + dir * 128 + u] = f2bf(h);
      }
      barrier_lgkm();
    }

  } else if (bid < nL1 + nL2){
    // ================= L2: H=64; proj (K=256) via MFMA lookahead. ==========
    const int i2 = bid - nL1;
    const int bloc = i2 >> 1, dir = i2 & 1;
    const unsigned short* h1i = (p2 ? h1r1 : h1r0) + (size_t)bloc * TL * 256;
    unsigned short* o2o = p2 ? o2r1 : o2r0;
    const int kc = tid & 7, u = tid >> 3;

    // recurrence weights fp32 (K=64 split kc*8) + bias
    float4 wr[4][2]; float bs[4];
    const float* WR = Whh2 + dir * 16384;
    #pragma unroll
    for (int tgt = 0; tgt < 4; ++tgt){
      const int row = tgt * 64 + u;
      wr[tgt][0] = *(const float4*)(WR + row * 64 + kc * 8);
      wr[tgt][1] = *(const float4*)(WR + row * 64 + kc * 8 + 4);
      bs[tgt] = bih2[dir * 256 + row] + bhh2[dir * 256 + row];
    }
    // MFMA B-frags: wave wv owns gate tiles {2wv, 2wv+1}; B[n][k] = Wih2[n][k]
    bfx8 Bf[2][8];
    const float* WP = Wih2 + dir * 65536;
    #pragma unroll
    for (int ntl = 0; ntl < 2; ++ntl){
      const int n = (2 * wv + ntl) * 16 + (lane & 15);
      #pragma unroll
      for (int Kf = 0; Kf < 8; ++Kf)
        Bf[ntl][Kf] = pack8(WP + n * 256 + Kf * 32 + (lane >> 4) * 8);
    }
    float* xs  = (float*)smem;                   // 2 bufs x 16 x 258 f
    float* h2b = (float*)(smem + 33024);         // 2 x 64 f
    if (tid < 64){ h2b[tid] = 0.0f; h2b[64 + tid] = 0.0f; }

    auto loadA = [&](int blk, uint4* a8){
      const int m  = lane & 15;
      const int pt = dir ? (TL - 1 - (blk * 16 + m)) : (blk * 16 + m);
      const unsigned short* base = h1i + (size_t)pt * 256 + (lane >> 4) * 8;
      #pragma unroll
      for (int Kf = 0; Kf < 8; ++Kf) a8[Kf] = *(const uint4*)(base + Kf * 32);
    };
    auto domfma = [&](uint4* a8, int buf){
      fx4 acc0 = {0.f,0.f,0.f,0.f}, acc1 = {0.f,0.f,0.f,0.f};
      #pragma unroll
      for (int Kf = 0; Kf < 8; ++Kf){
        bfx8 av; __builtin_memcpy(&av, &a8[Kf], 16);
        acc0 = __builtin_amdgcn_mfma_f32_16x16x32_bf16(av, Bf[0][Kf], acc0, 0, 0, 0);
        acc1 = __builtin_amdgcn_mfma_f32_16x16x32_bf16(av, Bf[1][Kf], acc1, 0, 0, 0);
      }
      const int c0 = (2 * wv) * 16 + (lane & 15);
      #pragma unroll
      for (int rr = 0; rr < 4; ++rr){
        const int row = (lane >> 4) * 4 + rr;
        xs[buf * 4128 + row * 258 + c0]      = acc0[rr];
        xs[buf * 4128 + row * 258 + c0 + 16] = acc1[rr];
      }
    };

    uint4 a8[8];
    loadA(0, a8); domfma(a8, 0);
    loadA(1, a8); domfma(a8, 1);
    __syncthreads();

    float cst = 0.0f;
    uint4 pf[8];
    for (int B = 0; B < 128; ++B){
      if (B + 2 < 128) loadA(B + 2, pf);      // issue; consumed after the 16 steps
      const int pb = B & 1;
      for (int s = 0; s < 16; ++s){
        const int t  = B * 16 + s;
        const int tt = dir ? (TL - 1 - t) : t;
        const int cur = t & 1;
        const float4* hv4 = (const float4*)(h2b + cur * 64) + kc * 2;
        const float4 hA = hv4[0], hB = hv4[1];
        float a0 = dot4(wr[0][1], hB, dot4(wr[0][0], hA, 0.f));
        float a1 = dot4(wr[1][1], hB, dot4(wr[1][0], hA, 0.f));
        float a2 = dot4(wr[2][1], hB, dot4(wr[2][0], hA, 0.f));
        float a3 = dot4(wr[3][1], hB, dot4(wr[3][0], hA, 0.f));
        a0 = swz4_add(dpp_xadd<0x4E>(dpp_xadd<0xB1>(a0)));
        a1 = swz4_add(dpp_xadd<0x4E>(dpp_xadd<0xB1>(a1)));
        a2 = swz4_add(dpp_xadd<0x4E>(dpp_xadd<0xB1>(a2)));
        a3 = swz4_add(dpp_xadd<0x4E>(dpp_xadd<0xB1>(a3)));
        if (kc == 0){
          const float* xr = xs + pb * 4128 + s * 258 + u;
          const float ig = sigf(a0 + xr[0]   + bs[0]);
          const float fg = sigf(a1 + xr[64]  + bs[1]);
          const float gg = tanhff(a2 + xr[128] + bs[2]);
          const float og = sigf(a3 + xr[192] + bs[3]);
          cst = fmaf(fg, cst, ig * gg);
          const float h = og * tanhff(cst);
          h2b[(cur ^ 1) * 64 + u] = h;
          o2o[((size_t)bloc * TL + tt) * 128 + dir * 64 + u] = f2bf(h);
        }
        barrier_lgkm();
      }
      if (B + 2 < 128) domfma(pf, pb);        // fills buf pb for block B+2
    }

  } else {
    // ================= L3: H=16; proj (K=128) via MFMA; T-mean in regs. ====
    // WG = 4 chains (same dir). 2 waves per chain.
    const int i3 = bid - nL1 - nL2;
    const int dir = i3 & 1, q4 = i3 >> 1;
    const int grp = tid >> 7, lt = tid & 127;
    const int bloc = q4 * 4 + grp;
    const unsigned short* o2i = (p3 ? o2r1 : o2r0) + (size_t)bloc * TL * 128;
    const int u = lt >> 3, j = lt & 7, gt = j >> 1, kc = j & 1;
    const int half = wv & 1;

    const float* WR = Whh3 + dir * 1024;
    const int r = gt * 16 + u;
    const float4 wr0 = *(const float4*)(WR + r * 16 + kc * 8);
    const float4 wr1 = *(const float4*)(WR + r * 16 + kc * 8 + 4);
    const float bsv = bih3[dir * 64 + r] + bhh3[dir * 64 + r];
    const int ubase = lane & ~7;
    const float bI = bperm(bsv, ubase + 0), bF = bperm(bsv, ubase + 2);
    const float bG = bperm(bsv, ubase + 4), bO = bperm(bsv, ubase + 6);

    bfx8 Bf[2][4];
    const float* WP = Wih3 + dir * 8192;     // (64,128)
    #pragma unroll
    for (int ntl = 0; ntl < 2; ++ntl){
      const int n = (2 * half + ntl) * 16 + (lane & 15);
      #pragma unroll
      for (int Kf = 0; Kf < 4; ++Kf)
        Bf[ntl][Kf] = pack8(WP + n * 128 + Kf * 32 + (lane >> 4) * 8);
    }
    float* xs  = (float*)smem + grp * 2112;  // per chain: 2 bufs x 16 x 66 f
    float* h3b = (float*)(smem + 33792) + grp * 32;
    if (lt < 32) h3b[lt] = 0.0f;

    auto loadA3 = [&](int blk, uint4* a4){
      const int m  = lane & 15;
      const int pt = dir ? (TL - 1 - (blk * 16 + m)) : (blk * 16 + m);
      const unsigned short* base = o2i + (size_t)pt * 128 + (lane >> 4) * 8;
      #pragma unroll
      for (int Kf = 0; Kf < 4; ++Kf) a4[Kf] = *(const uint4*)(base + Kf * 32);
    };
    auto domfma3 = [&](uint4* a4, int buf){
      fx4 acc0 = {0.f,0.f,0.f,0.f}, acc1 = {0.f,0.f,0.f,0.f};
      #pragma unroll
      for (int Kf = 0; Kf < 4; ++Kf){
        bfx8 av; __builtin_memcpy(&av, &a4[Kf], 16);
        acc0 = __builtin_amdgcn_mfma_f32_16x16x32_bf16(av, Bf[0][Kf], acc0, 0, 0, 0);
        acc1 = __builtin_amdgcn_mfma_f32_16x16x32_bf16(av, Bf[1][Kf], acc1, 0, 0, 0);
      }
      const int c0 = (2 * half) * 16 + (lane & 15);
      #pragma unroll
      for (int rr = 0; rr < 4; ++rr){
        const int row = (lane >> 4) * 4 + rr;
        xs[buf * 1056 + row * 66 + c0]      = acc0[rr];
        xs[buf * 1056 + row * 66 + c0 + 16] = acc1[rr];
      }
    };

    uint4 a4[4];
    loadA3(0, a4); domfma3(a4, 0);
    loadA3(1, a4); domfma3(a4, 1);
    __syncthreads();

    float cst = 0.0f, msum = 0.0f;
    uint4 pf[4];
    for (int B = 0; B < 128; ++B){
      if (B + 2 < 128) loadA3(B + 2, pf);
      const int pb = B & 1;
      for (int s = 0; s < 16; ++s){
        const int t = B * 16 + s;
        const int cur = t & 1;
        const float4* h3p = (const float4*)(h3b + cur * 16 + kc * 8);
        float acc = dot4(wr1, h3p[1], dot4(wr0, h3p[0], 0.f));
        acc = dpp_xadd<0xB1>(acc);
        const float gI = bperm(acc, ubase + 0), gF = bperm(acc, ubase + 2);
        const float gG = bperm(acc, ubase + 4), gO = bperm(acc, ubase + 6);
        if (j == 0){
          const float* xr = xs + pb * 1056 + s * 66 + u;
          const float ig = sigf(gI + bI + xr[0]);
          const float fg = sigf(gF + bF + xr[16]);
          const float gg = tanhff(gG + bG + xr[32]);
          const float og = sigf(gO + bO + xr[48]);
          cst = fmaf(fg, cst, ig * gg);
          const float h = og * tanhff(cst);
          h3b[(cur ^ 1) * 16 + u] = h;
          msum += h;
        }
        barrier_lgkm();
      }
      if (B + 2 < 128) domfma3(pf, pb);
    }
    if (j == 0) sums[(size_t)(cb3 + bloc) * 32 + dir * 16 + u] = msum;
  }
}

// ---------------- head: mean (pre-summed) + MLP, one 64-thr WG per batch
__global__ __launch_bounds__(64) void head_kernel(
    const float* __restrict__ sums,
    const float* __restrict__ hW1, const float* __restrict__ hb1,
    const float* __restrict__ hW2, const float* __restrict__ hb2,
    const float* __restrict__ hW3, const float* __restrict__ hb3,
    float* __restrict__ out)
{
  __shared__ float m[32], h1s[64], h2s[16];
  const int tid = threadIdx.x, b = blockIdx.x;
  if (tid < 32) m[tid] = sums[b * 32 + tid] * (1.0f / 2048.0f);
  __syncthreads();
  {
    float a = hb1[tid];
    #pragma unroll
    for (int k = 0; k < 32; ++k) a = fmaf(m[k], hW1[tid * 32 + k], a);
    h1s[tid] = fmaxf(a, 0.0f);
  }
  __syncthreads();
  if (tid < 16){
    float a = hb2[tid];
    #pragma unroll
    for (int k = 0; k < 64; ++k) a = fmaf(h1s[k], hW2[tid * 64 + k], a);
    h2s[tid] = fmaxf(a, 0.0f);
  }
  __syncthreads();
  if (tid < 20){
    float a = hb3[tid];
    #pragma unroll
    for (int k = 0; k < 16; ++k) a = fmaf(h2s[k], hW3[tid * 16 + k], a);
    out[b * 20 + tid] = a;
  }
}

extern "C" void kernel_launch(void* const* d_in, const int* in_sizes, int n_in,
                              void* d_out, int out_size, void* d_ws, size_t ws_size,
                              hipStream_t stream) {
  (void)in_sizes; (void)n_in; (void)out_size;
  const float* x    = (const float*)d_in[0];
  const float* Wih1 = (const float*)d_in[1];
  const float* Whh1 = (const float*)d_in[2];
  const float* bih1 = (const float*)d_in[3];
  const float* bhh1 = (const float*)d_in[4];
  const float* Wih2 = (const float*)d_in[5];
  const float* Whh2 = (const float*)d_in[6];
  const float* bih2 = (const float*)d_in[7];
  const float* bhh2 = (const float*)d_in[8];
  const float* Wih3 = (const float*)d_in[9];
  const float* Whh3 = (const float*)d_in[10];
  const float* bih3 = (const float*)d_in[11];
  const float* bhh3 = (const float*)d_in[12];
  const float* hW1  = (const float*)d_in[13];
  const float* hb1  = (const float*)d_in[14];
  const float* hW2  = (const float*)d_in[15];
  const float* hb2  = (const float*)d_in[16];
  const float* hW3  = (const float*)d_in[17];
  const float* hb3  = (const float*)d_in[18];
  unsigned char* ws = (unsigned char*)d_ws;

  if (ws_size >= 402685952ull) {
    // ===== Tier 1: fully serialized, full-width stages, 2 blocks/CU. =====
    // h1 (256,2048,256) bf16 = 268,435,456 B | o2 (256,2048,128) bf16 =
    // 134,217,728 B | sums (256,32) f32 = 32,768 B. Total 402,685,952 B.
    unsigned short* h1 = (unsigned short*)ws;
    unsigned short* o2 = (unsigned short*)(ws + 268435456u);
    float* sums = (float*)(ws + 402653184u);
    mega_kernel<<<dim3(512), dim3(512), 0, stream>>>(   // L1: all 512 chains
        512, 0, 0, 0, 0, 0, 0, 0, 0,
        x, Wih1, Whh1, bih1, bhh1, Wih2, Whh2, bih2, bhh2,
        Wih3, Whh3, bih3, bhh3, h1, h1, o2, o2, sums);
    mega_kernel<<<dim3(512), dim3(512), 0, stream>>>(   // L2: all 512 chains
        0, 512, 0, 0, 0, 0, 0, 0, 0,
        x, Wih1, Whh1, bih1, bhh1, Wih2, Whh2, bih2, bhh2,
        Wih3, Whh3, bih3, bhh3, h1, h1, o2, o2, sums);
    mega_kernel<<<dim3(128), dim3(512), 0, stream>>>(   // L3: 4 chains/WG
        0, 0, 128, 0, 0, 0, 0, 0, 0,
        x, Wih1, Whh1, bih1, bhh1, Wih2, Whh2, bih2, bhh2,
        Wih3, Whh3, bih3, bhh3, h1, h1, o2, o2, sums);
    head_kernel<<<dim3(256), dim3(64), 0, stream>>>(
        sums, hW1, hb1, hW2, hb2, hW3, hb3, (float*)d_out);
    return;
  }

  if (ws_size >= 335577088ull) {
    // ===== Tier 2: full-width L1, then L2/L3 in half-B passes reusing one
    // 64 MiB o2 half-buffer. h1 268,435,456 | o2half 67,108,864 | sums.
    unsigned short* h1   = (unsigned short*)ws;
    unsigned short* h1hi = h1 + (size_t)128 * TL * 256;   // batches 128..255
    unsigned short* o2   = (unsigned short*)(ws + 268435456u);
    float* sums = (float*)(ws + 335544320u);
    mega_kernel<<<dim3(512), dim3(512), 0, stream>>>(   // L1: all
        512, 0, 0, 0, 0, 0, 0, 0, 0,
        x, Wih1, Whh1, bih1, bhh1, Wih2, Whh2, bih2, bhh2,
        Wih3, Whh3, bih3, bhh3, h1, h1, o2, o2, sums);
    mega_kernel<<<dim3(256), dim3(512), 0, stream>>>(   // L2: b 0..127
        0, 256, 0, 0, 0, 0, 0, 0, 0,
        x, Wih1, Whh1, bih1, bhh1, Wih2, Whh2, bih2, bhh2,
        Wih3, Whh3, bih3, bhh3, h1, h1, o2, o2, sums);
    mega_kernel<<<dim3(64), dim3(512), 0, stream>>>(    // L3: b 0..127
        0, 0, 64, 0, 0, 0, 0, 0, 0,
        x, Wih1, Whh1, bih1, bhh1, Wih2, Whh2, bih2, bhh2,
        Wih3, Whh3, bih3, bhh3, h1, h1, o2, o2, sums);
    mega_kernel<<<dim3(256), dim3(512), 0, stream>>>(   // L2: b 128..255
        0, 256, 0, 0, 0, 0, 0, 0, 0,
        x, Wih1, Whh1, bih1, bhh1, Wih2, Whh2, bih2, bhh2,
        Wih3, Whh3, bih3, bhh3, h1hi, h1hi, o2, o2, sums);
    mega_kernel<<<dim3(64), dim3(512), 0, stream>>>(    // L3: b 128..255
        0, 0, 64, 0, 0, 128, 0, 0, 0,
        x, Wih1, Whh1, bih1, bhh1, Wih2, Whh2, bih2, bhh2,
        Wih3, Whh3, bih3, bhh3, h1, h1, o2, o2, sums);
    head_kernel<<<dim3(256), dim3(64), 0, stream>>>(
        sums, hW1, hb1, hW2, hb2, hW3, hb3, (float*)d_out);
    return;
  }

  // ===== Tier 3: pipelined fallback, chunks {52,52,52,52,48} (was 6x48).
  // One fewer L1-bearing dispatch. Rings: h1 2x 54,525,952 | o2 2x 27,262,976
  // | sums. Total 163,610,624 B <= 167.8 MB proven available.
  {
    unsigned short* h1r0 = (unsigned short*)ws;
    unsigned short* h1r1 = h1r0 + (size_t)52 * TL * 256;
    unsigned short* o2r0 = (unsigned short*)(ws + 109051904u);
    unsigned short* o2r1 = o2r0 + (size_t)52 * TL * 128;
    float* sums = (float*)(ws + 163577856u);

    const int cs[5] = {52, 52, 52, 52, 48};
    const int co[5] = {0, 52, 104, 156, 208};
    for (int k = 0; k < 7; ++k){
      const int a1 = (k < 5) ? cs[k] : 0;
      const int a2 = (k >= 1 && k < 6) ? cs[k - 1] : 0;
      const int a3 = (k >= 2) ? cs[k - 2] : 0;
      const int nL1 = 2 * a1, nL2 = 2 * a2, nL3 = a3 / 2;
      mega_kernel<<<dim3(nL1 + nL2 + nL3), dim3(512), 0, stream>>>(
          nL1, nL2, nL3,
          (k < 5) ? co[k] : 0, (k >= 1 && k < 6) ? co[k - 1] : 0,
          (k >= 2) ? co[k - 2] : 0,
          k & 1, (k + 1) & 1, k & 1,
          x, Wih1, Whh1, bih1, bhh1, Wih2, Whh2, bih2, bhh2,
          Wih3, Whh3, bih3, bhh3, h1r0, h1r1, o2r0, o2r1, sums);
    }
    head_kernel<<<dim3(256), dim3(64), 0, stream>>>(
        sums, hW1, hb1, hW2, hb2, hW3, hb3, (float*)d_out);
  }
}

// Round 3
// 8648.561 us; speedup vs baseline: 3.0846x; 1.0020x over previous
//
#include <hip/hip_runtime.h>

#define TL 2048

typedef __attribute__((ext_vector_type(8))) short bfx8;
typedef __attribute__((ext_vector_type(4))) float fx4;

__device__ __forceinline__ float sigf(float x){ return __builtin_amdgcn_rcpf(1.0f + __expf(-x)); }
__device__ __forceinline__ float tanhff(float x){ return fmaf(2.0f, sigf(2.0f*x), -1.0f); }

template<int CTRL>
__device__ __forceinline__ float dpp_xadd(float v){
  int s = __builtin_amdgcn_update_dpp(0, __float_as_int(v), CTRL, 0xF, 0xF, true);
  return v + __int_as_float(s);
}
__device__ __forceinline__ float swz4_add(float v){
  int s = __builtin_amdgcn_ds_swizzle(__float_as_int(v), 0x101F);
  return v + __int_as_float(s);
}
__device__ __forceinline__ float bperm(float v, int srclane){
  return __int_as_float(__builtin_amdgcn_ds_bpermute(srclane << 2, __float_as_int(v)));
}
__device__ __forceinline__ unsigned short f2bf(float f){   // RNE fp32->bf16
  unsigned int u = __float_as_uint(f);
  u += 0x7fffu + ((u >> 16) & 1u);
  return (unsigned short)(u >> 16);
}
__device__ __forceinline__ float dot4(float4 a, float4 b, float acc){
  acc = fmaf(a.x, b.x, acc); acc = fmaf(a.y, b.y, acc);
  acc = fmaf(a.z, b.z, acc); acc = fmaf(a.w, b.w, acc);
  return acc;
}
// LDS-only barrier: do NOT drain vmcnt (global h-stores stay in flight).
__device__ __forceinline__ void barrier_lgkm(){
  asm volatile("s_waitcnt lgkmcnt(0)\ns_barrier" ::: "memory");
}
__device__ __forceinline__ bfx8 pack8(const float* p){
  bfx8 r;
  #pragma unroll
  for (int i = 0; i < 8; ++i) r[i] = (short)f2bf(p[i]);
  return r;
}

// Uber-kernel; segments selected per-block by [nL1 | nL2 | nL3]:
//   blockIdx [0,nL1)            : L1 scan (fp32 VALU, D=2 folded), h1 out bf16
//   blockIdx [nL1,nL1+nL2)      : L2 scan, Wih2 proj via MFMA 16-step lookahead
//   blockIdx [nL1+nL2, +nL3)    : L3 scan, Wih3 proj via MFMA + T-mean accumulate
// __launch_bounds__(512,2): DO NOT raise the min-waves arg. (512,4) caps the
// allocator at 64 VGPR (round-1 regression: spill, 45 ms L1 dispatch). At
// (512,2) the compiler settles at 120 VGPR, which ALREADY admits 4 waves/EU
// (m69 occupancy steps: <=128 VGPR -> 4 waves/SIMD) = 2 blocks/CU co-resident
// when the grid exceeds 256 blocks, with zero spill.
__global__ __launch_bounds__(512, 2) void mega_kernel(
    int nL1, int nL2, int nL3, int cb1, int cb2, int cb3, int p1, int p2, int p3,
    const float* __restrict__ x,
    const float* __restrict__ Wih1, const float* __restrict__ Whh1,
    const float* __restrict__ bih1, const float* __restrict__ bhh1,
    const float* __restrict__ Wih2, const float* __restrict__ Whh2,
    const float* __restrict__ bih2, const float* __restrict__ bhh2,
    const float* __restrict__ Wih3, const float* __restrict__ Whh3,
    const float* __restrict__ bih3, const float* __restrict__ bhh3,
    unsigned short* __restrict__ h1r0, unsigned short* __restrict__ h1r1,
    unsigned short* __restrict__ o2r0, unsigned short* __restrict__ o2r1,
    float* __restrict__ sums)
{
  __shared__ __align__(16) unsigned char smem[34816];
  const int tid  = threadIdx.x;
  const int bid  = blockIdx.x;
  const int lane = tid & 63;
  const int wv   = tid >> 6;

  if (bid < nL1){
    // ================= L1: H=128, D=2 folded. WG = one (b,dir) chain. ======
    const int bloc = bid >> 1, dir = bid & 1;
    unsigned short* h1o = p1 ? h1r1 : h1r0;
    const int kc = tid & 3, u = tid >> 2;

    float4 w[4][8];
    const float* Wh = Whh1 + dir * 65536;
    #pragma unroll
    for (int g = 0; g < 4; ++g){
      const float* row = Wh + (g * 128 + u) * 128 + kc * 32;
      #pragma unroll
      for (int q = 0; q < 8; ++q){
        const int ro = (q + 2 * kc) & 7;
        w[g][q] = *(const float4*)(row + ro * 4);
      }
    }
    float xwA[4], xwB[4], bs[4];
    #pragma unroll
    for (int g = 0; g < 4; ++g){
      const int r = g * 128 + u;
      xwA[g] = Wih1[dir * 1024 + r * 2];
      xwB[g] = Wih1[dir * 1024 + r * 2 + 1];
      bs[g]  = bih1[dir * 512 + r] + bhh1[dir * 512 + r];
    }
    float* xlds = (float*)smem;                  // 4096 f (full x row)
    float* hbuf = (float*)(smem + 16384);        // 2 x 128 f
    {
      const float* xb = x + (size_t)(cb1 + bloc) * (TL * 2);
      for (int idx = tid; idx < TL * 2; idx += 512) xlds[idx] = xb[idx];
    }
    if (tid < 128){ hbuf[tid] = 0.0f; hbuf[128 + tid] = 0.0f; }
    __syncthreads();

    float cst = 0.0f;
    for (int t = 0; t < TL; ++t){
      const int tt  = dir ? (TL - 1 - t) : t;
      const int cur = t & 1;
      const float4* hp = (const float4*)(hbuf + cur * 128) + kc * 8;
      float a0 = 0.f, a1 = 0.f, a2 = 0.f, a3 = 0.f;
      #pragma unroll
      for (int q = 0; q < 8; ++q){
        const float4 hv = hp[(q + 2 * kc) & 7];
        a0 = dot4(w[0][q], hv, a0);
        a1 = dot4(w[1][q], hv, a1);
        a2 = dot4(w[2][q], hv, a2);
        a3 = dot4(w[3][q], hv, a3);
      }
      a0 = dpp_xadd<0x4E>(dpp_xadd<0xB1>(a0));
      a1 = dpp_xadd<0x4E>(dpp_xadd<0xB1>(a1));
      a2 = dpp_xadd<0x4E>(dpp_xadd<0xB1>(a2));
      a3 = dpp_xadd<0x4E>(dpp_xadd<0xB1>(a3));
      if (kc == 0){
        const float x0 = xlds[tt * 2], x1 = xlds[tt * 2 + 1];
        const float p0 = a0 + fmaf(xwA[0], x0, fmaf(xwB[0], x1, bs[0]));
        const float p1 = a1 + fmaf(xwA[1], x0, fmaf(xwB[1], x1, bs[1]));
        const float p2 = a2 + fmaf(xwA[2], x0, fmaf(xwB[2], x1, bs[2]));
        const float p3 = a3 + fmaf(xwA[3], x0, fmaf(xwB[3], x1, bs[3]));
        const float ig = sigf(p0), fg = sigf(p1), gg = tanhff(p2), og = sigf(p3);
        cst = fmaf(fg, cst, ig * gg);
        const float h = og * tanhff(cst);
        hbuf[(cur ^ 1) * 128 + u] = h;
        h1o[((size_t)bloc * TL + tt) * 256 + dir * 128 + u] = f2bf(h);
      }
      barrier_lgkm();
    }

  } else if (bid < nL1 + nL2){
    // ================= L2: H=64; proj (K=256) via MFMA lookahead. ==========
    const int i2 = bid - nL1;
    const int bloc = i2 >> 1, dir = i2 & 1;
    const unsigned short* h1i = (p2 ? h1r1 : h1r0) + (size_t)bloc * TL * 256;
    unsigned short* o2o = p2 ? o2r1 : o2r0;
    const int kc = tid & 7, u = tid >> 3;

    // recurrence weights fp32 (K=64 split kc*8) + bias
    float4 wr[4][2]; float bs[4];
    const float* WR = Whh2 + dir * 16384;
    #pragma unroll
    for (int tgt = 0; tgt < 4; ++tgt){
      const int row = tgt * 64 + u;
      wr[tgt][0] = *(const float4*)(WR + row * 64 + kc * 8);
      wr[tgt][1] = *(const float4*)(WR + row * 64 + kc * 8 + 4);
      bs[tgt] = bih2[dir * 256 + row] + bhh2[dir * 256 + row];
    }
    // MFMA B-frags: wave wv owns gate tiles {2wv, 2wv+1}; B[n][k] = Wih2[n][k]
    bfx8 Bf[2][8];
    const float* WP = Wih2 + dir * 65536;
    #pragma unroll
    for (int ntl = 0; ntl < 2; ++ntl){
      const int n = (2 * wv + ntl) * 16 + (lane & 15);
      #pragma unroll
      for (int Kf = 0; Kf < 8; ++Kf)
        Bf[ntl][Kf] = pack8(WP + n * 256 + Kf * 32 + (lane >> 4) * 8);
    }
    float* xs  = (float*)smem;                   // 2 bufs x 16 x 258 f
    float* h2b = (float*)(smem + 33024);         // 2 x 64 f
    if (tid < 64){ h2b[tid] = 0.0f; h2b[64 + tid] = 0.0f; }

    auto loadA = [&](int blk, uint4* a8){
      const int m  = lane & 15;
      const int pt = dir ? (TL - 1 - (blk * 16 + m)) : (blk * 16 + m);
      const unsigned short* base = h1i + (size_t)pt * 256 + (lane >> 4) * 8;
      #pragma unroll
      for (int Kf = 0; Kf < 8; ++Kf) a8[Kf] = *(const uint4*)(base + Kf * 32);
    };
    auto domfma = [&](uint4* a8, int buf){
      fx4 acc0 = {0.f,0.f,0.f,0.f}, acc1 = {0.f,0.f,0.f,0.f};
      #pragma unroll
      for (int Kf = 0; Kf < 8; ++Kf){
        bfx8 av; __builtin_memcpy(&av, &a8[Kf], 16);
        acc0 = __builtin_amdgcn_mfma_f32_16x16x32_bf16(av, Bf[0][Kf], acc0, 0, 0, 0);
        acc1 = __builtin_amdgcn_mfma_f32_16x16x32_bf16(av, Bf[1][Kf], acc1, 0, 0, 0);
      }
      const int c0 = (2 * wv) * 16 + (lane & 15);
      #pragma unroll
      for (int rr = 0; rr < 4; ++rr){
        const int row = (lane >> 4) * 4 + rr;
        xs[buf * 4128 + row * 258 + c0]      = acc0[rr];
        xs[buf * 4128 + row * 258 + c0 + 16] = acc1[rr];
      }
    };

    uint4 a8[8];
    loadA(0, a8); domfma(a8, 0);
    loadA(1, a8); domfma(a8, 1);
    __syncthreads();

    float cst = 0.0f;
    uint4 pf[8];
    for (int B = 0; B < 128; ++B){
      if (B + 2 < 128) loadA(B + 2, pf);      // issue; consumed after the 16 steps
      const int pb = B & 1;
      for (int s = 0; s < 16; ++s){
        const int t  = B * 16 + s;
        const int tt = dir ? (TL - 1 - t) : t;
        const int cur = t & 1;
        const float4* hv4 = (const float4*)(h2b + cur * 64) + kc * 2;
        const float4 hA = hv4[0], hB = hv4[1];
        float a0 = dot4(wr[0][1], hB, dot4(wr[0][0], hA, 0.f));
        float a1 = dot4(wr[1][1], hB, dot4(wr[1][0], hA, 0.f));
        float a2 = dot4(wr[2][1], hB, dot4(wr[2][0], hA, 0.f));
        float a3 = dot4(wr[3][1], hB, dot4(wr[3][0], hA, 0.f));
        a0 = swz4_add(dpp_xadd<0x4E>(dpp_xadd<0xB1>(a0)));
        a1 = swz4_add(dpp_xadd<0x4E>(dpp_xadd<0xB1>(a1)));
        a2 = swz4_add(dpp_xadd<0x4E>(dpp_xadd<0xB1>(a2)));
        a3 = swz4_add(dpp_xadd<0x4E>(dpp_xadd<0xB1>(a3)));
        if (kc == 0){
          const float* xr = xs + pb * 4128 + s * 258 + u;
          const float ig = sigf(a0 + xr[0]   + bs[0]);
          const float fg = sigf(a1 + xr[64]  + bs[1]);
          const float gg = tanhff(a2 + xr[128] + bs[2]);
          const float og = sigf(a3 + xr[192] + bs[3]);
          cst = fmaf(fg, cst, ig * gg);
          const float h = og * tanhff(cst);
          h2b[(cur ^ 1) * 64 + u] = h;
          o2o[((size_t)bloc * TL + tt) * 128 + dir * 64 + u] = f2bf(h);
        }
        barrier_lgkm();
      }
      if (B + 2 < 128) domfma(pf, pb);        // fills buf pb for block B+2
    }

  } else {
    // ================= L3: H=16; proj (K=128) via MFMA; T-mean in regs. ====
    // WG = 4 chains (same dir). 2 waves per chain.  NOTE: chunk sizes fed to
    // the L3 stage must be multiples of 4 (4 chains/WG packing).
    const int i3 = bid - nL1 - nL2;
    const int dir = i3 & 1, q4 = i3 >> 1;
    const int grp = tid >> 7, lt = tid & 127;
    const int bloc = q4 * 4 + grp;
    const unsigned short* o2i = (p3 ? o2r1 : o2r0) + (size_t)bloc * TL * 128;
    const int u = lt >> 3, j = lt & 7, gt = j >> 1, kc = j & 1;
    const int half = wv & 1;

    const float* WR = Whh3 + dir * 1024;
    const int r = gt * 16 + u;
    const float4 wr0 = *(const float4*)(WR + r * 16 + kc * 8);
    const float4 wr1 = *(const float4*)(WR + r * 16 + kc * 8 + 4);
    const float bsv = bih3[dir * 64 + r] + bhh3[dir * 64 + r];
    const int ubase = lane & ~7;
    const float bI = bperm(bsv, ubase + 0), bF = bperm(bsv, ubase + 2);
    const float bG = bperm(bsv, ubase + 4), bO = bperm(bsv, ubase + 6);

    bfx8 Bf[2][4];
    const float* WP = Wih3 + dir * 8192;     // (64,128)
    #pragma unroll
    for (int ntl = 0; ntl < 2; ++ntl){
      const int n = (2 * half + ntl) * 16 + (lane & 15);
      #pragma unroll
      for (int Kf = 0; Kf < 4; ++Kf)
        Bf[ntl][Kf] = pack8(WP + n * 128 + Kf * 32 + (lane >> 4) * 8);
    }
    float* xs  = (float*)smem + grp * 2112;  // per chain: 2 bufs x 16 x 66 f
    float* h3b = (float*)(smem + 33792) + grp * 32;
    if (lt < 32) h3b[lt] = 0.0f;

    auto loadA3 = [&](int blk, uint4* a4){
      const int m  = lane & 15;
      const int pt = dir ? (TL - 1 - (blk * 16 + m)) : (blk * 16 + m);
      const unsigned short* base = o2i + (size_t)pt * 128 + (lane >> 4) * 8;
      #pragma unroll
      for (int Kf = 0; Kf < 4; ++Kf) a4[Kf] = *(const uint4*)(base + Kf * 32);
    };
    auto domfma3 = [&](uint4* a4, int buf){
      fx4 acc0 = {0.f,0.f,0.f,0.f}, acc1 = {0.f,0.f,0.f,0.f};
      #pragma unroll
      for (int Kf = 0; Kf < 4; ++Kf){
        bfx8 av; __builtin_memcpy(&av, &a4[Kf], 16);
        acc0 = __builtin_amdgcn_mfma_f32_16x16x32_bf16(av, Bf[0][Kf], acc0, 0, 0, 0);
        acc1 = __builtin_amdgcn_mfma_f32_16x16x32_bf16(av, Bf[1][Kf], acc1, 0, 0, 0);
      }
      const int c0 = (2 * half) * 16 + (lane & 15);
      #pragma unroll
      for (int rr = 0; rr < 4; ++rr){
        const int row = (lane >> 4) * 4 + rr;
        xs[buf * 1056 + row * 66 + c0]      = acc0[rr];
        xs[buf * 1056 + row * 66 + c0 + 16] = acc1[rr];
      }
    };

    uint4 a4[4];
    loadA3(0, a4); domfma3(a4, 0);
    loadA3(1, a4); domfma3(a4, 1);
    __syncthreads();

    float cst = 0.0f, msum = 0.0f;
    uint4 pf[4];
    for (int B = 0; B < 128; ++B){
      if (B + 2 < 128) loadA3(B + 2, pf);
      const int pb = B & 1;
      for (int s = 0; s < 16; ++s){
        const int t = B * 16 + s;
        const int cur = t & 1;
        const float4* h3p = (const float4*)(h3b + cur * 16 + kc * 8);
        float acc = dot4(wr1, h3p[1], dot4(wr0, h3p[0], 0.f));
        acc = dpp_xadd<0xB1>(acc);
        const float gI = bperm(acc, ubase + 0), gF = bperm(acc, ubase + 2);
        const float gG = bperm(acc, ubase + 4), gO = bperm(acc, ubase + 6);
        if (j == 0){
          const float* xr = xs + pb * 1056 + s * 66 + u;
          const float ig = sigf(gI + bI + xr[0]);
          const float fg = sigf(gF + bF + xr[16]);
          const float gg = tanhff(gG + bG + xr[32]);
          const float og = sigf(gO + bO + xr[48]);
          cst = fmaf(fg, cst, ig * gg);
          const float h = og * tanhff(cst);
          h3b[(cur ^ 1) * 16 + u] = h;
          msum += h;
        }
        barrier_lgkm();
      }
      if (B + 2 < 128) domfma3(pf, pb);
    }
    if (j == 0) sums[(size_t)(cb3 + bloc) * 32 + dir * 16 + u] = msum;
  }
}

// ---------------- head: mean (pre-summed) + MLP, one 64-thr WG per batch
__global__ __launch_bounds__(64) void head_kernel(
    const float* __restrict__ sums,
    const float* __restrict__ hW1, const float* __restrict__ hb1,
    const float* __restrict__ hW2, const float* __restrict__ hb2,
    const float* __restrict__ hW3, const float* __restrict__ hb3,
    float* __restrict__ out)
{
  __shared__ float m[32], h1s[64], h2s[16];
  const int tid = threadIdx.x, b = blockIdx.x;
  if (tid < 32) m[tid] = sums[b * 32 + tid] * (1.0f / 2048.0f);
  __syncthreads();
  {
    float a = hb1[tid];
    #pragma unroll
    for (int k = 0; k < 32; ++k) a = fmaf(m[k], hW1[tid * 32 + k], a);
    h1s[tid] = fmaxf(a, 0.0f);
  }
  __syncthreads();
  if (tid < 16){
    float a = hb2[tid];
    #pragma unroll
    for (int k = 0; k < 64; ++k) a = fmaf(h1s[k], hW2[tid * 64 + k], a);
    h2s[tid] = fmaxf(a, 0.0f);
  }
  __syncthreads();
  if (tid < 20){
    float a = hb3[tid];
    #pragma unroll
    for (int k = 0; k < 16; ++k) a = fmaf(h2s[k], hW3[tid * 16 + k], a);
    out[b * 20 + tid] = a;
  }
}

extern "C" void kernel_launch(void* const* d_in, const int* in_sizes, int n_in,
                              void* d_out, int out_size, void* d_ws, size_t ws_size,
                              hipStream_t stream) {
  (void)in_sizes; (void)n_in; (void)out_size;
  const float* x    = (const float*)d_in[0];
  const float* Wih1 = (const float*)d_in[1];
  const float* Whh1 = (const float*)d_in[2];
  const float* bih1 = (const float*)d_in[3];
  const float* bhh1 = (const float*)d_in[4];
  const float* Wih2 = (const float*)d_in[5];
  const float* Whh2 = (const float*)d_in[6];
  const float* bih2 = (const float*)d_in[7];
  const float* bhh2 = (const float*)d_in[8];
  const float* Wih3 = (const float*)d_in[9];
  const float* Whh3 = (const float*)d_in[10];
  const float* bih3 = (const float*)d_in[11];
  const float* bhh3 = (const float*)d_in[12];
  const float* hW1  = (const float*)d_in[13];
  const float* hb1  = (const float*)d_in[14];
  const float* hW2  = (const float*)d_in[15];
  const float* hb2  = (const float*)d_in[16];
  const float* hW3  = (const float*)d_in[17];
  const float* hb3  = (const float*)d_in[18];
  unsigned char* ws = (unsigned char*)d_ws;

  if (ws_size >= 402685952ull) {
    // ===== Tier 1: fully serialized, full-width stages, 2 blocks/CU. =====
    // h1 (256,2048,256) bf16 = 268,435,456 B | o2 (256,2048,128) bf16 =
    // 134,217,728 B | sums (256,32) f32 = 32,768 B. Total 402,685,952 B.
    unsigned short* h1 = (unsigned short*)ws;
    unsigned short* o2 = (unsigned short*)(ws + 268435456u);
    float* sums = (float*)(ws + 402653184u);
    mega_kernel<<<dim3(512), dim3(512), 0, stream>>>(   // L1: all 512 chains
        512, 0, 0, 0, 0, 0, 0, 0, 0,
        x, Wih1, Whh1, bih1, bhh1, Wih2, Whh2, bih2, bhh2,
        Wih3, Whh3, bih3, bhh3, h1, h1, o2, o2, sums);
    mega_kernel<<<dim3(512), dim3(512), 0, stream>>>(   // L2: all 512 chains
        0, 512, 0, 0, 0, 0, 0, 0, 0,
        x, Wih1, Whh1, bih1, bhh1, Wih2, Whh2, bih2, bhh2,
        Wih3, Whh3, bih3, bhh3, h1, h1, o2, o2, sums);
    mega_kernel<<<dim3(128), dim3(512), 0, stream>>>(   // L3: 4 chains/WG
        0, 0, 128, 0, 0, 0, 0, 0, 0,
        x, Wih1, Whh1, bih1, bhh1, Wih2, Whh2, bih2, bhh2,
        Wih3, Whh3, bih3, bhh3, h1, h1, o2, o2, sums);
    head_kernel<<<dim3(256), dim3(64), 0, stream>>>(
        sums, hW1, hb1, hW2, hb2, hW3, hb3, (float*)d_out);
    return;
  }

  if (ws_size >= 335577088ull) {
    // ===== Tier 2: full-width L1, then L2/L3 in half-B passes reusing one
    // 64 MiB o2 half-buffer. h1 268,435,456 | o2half 67,108,864 | sums.
    unsigned short* h1   = (unsigned short*)ws;
    unsigned short* h1hi = h1 + (size_t)128 * TL * 256;   // batches 128..255
    unsigned short* o2   = (unsigned short*)(ws + 268435456u);
    float* sums = (float*)(ws + 335544320u);
    mega_kernel<<<dim3(512), dim3(512), 0, stream>>>(   // L1: all
        512, 0, 0, 0, 0, 0, 0, 0, 0,
        x, Wih1, Whh1, bih1, bhh1, Wih2, Whh2, bih2, bhh2,
        Wih3, Whh3, bih3, bhh3, h1, h1, o2, o2, sums);
    mega_kernel<<<dim3(256), dim3(512), 0, stream>>>(   // L2: b 0..127
        0, 256, 0, 0, 0, 0, 0, 0, 0,
        x, Wih1, Whh1, bih1, bhh1, Wih2, Whh2, bih2, bhh2,
        Wih3, Whh3, bih3, bhh3, h1, h1, o2, o2, sums);
    mega_kernel<<<dim3(64), dim3(512), 0, stream>>>(    // L3: b 0..127
        0, 0, 64, 0, 0, 0, 0, 0, 0,
        x, Wih1, Whh1, bih1, bhh1, Wih2, Whh2, bih2, bhh2,
        Wih3, Whh3, bih3, bhh3, h1, h1, o2, o2, sums);
    mega_kernel<<<dim3(256), dim3(512), 0, stream>>>(   // L2: b 128..255
        0, 256, 0, 0, 0, 0, 0, 0, 0,
        x, Wih1, Whh1, bih1, bhh1, Wih2, Whh2, bih2, bhh2,
        Wih3, Whh3, bih3, bhh3, h1hi, h1hi, o2, o2, sums);
    mega_kernel<<<dim3(64), dim3(512), 0, stream>>>(    // L3: b 128..255
        0, 0, 64, 0, 0, 128, 0, 0, 0,
        x, Wih1, Whh1, bih1, bhh1, Wih2, Whh2, bih2, bhh2,
        Wih3, Whh3, bih3, bhh3, h1, h1, o2, o2, sums);
    head_kernel<<<dim3(256), dim3(64), 0, stream>>>(
        sums, hW1, hb1, hW2, hb2, hW3, hb3, (float*)d_out);
    return;
  }

  // ===== Ring pipeline, capacity graded by ws_size. Footprint(C) =
  // C*3,145,728 + 32,768 B. Dispatches = nchunks + 2; each ~1.4 ms
  // (latency-bound chain scan) so fewer chunks == less time. All chunk
  // sizes must be multiples of 4 (L3 packs 4 chains per WG).
  {
    int cs[5]; int nch; size_t C;
    if (ws_size >= 276856832ull)      { C = 88; nch = 3; cs[0] = 88; cs[1] = 84; cs[2] = 84; }
    else if (ws_size >= 201359360ull) { C = 64; nch = 4; cs[0] = cs[1] = cs[2] = cs[3] = 64; }
    else                              { C = 52; nch = 5; cs[0] = cs[1] = cs[2] = cs[3] = 52; cs[4] = 48; }

    unsigned short* h1r0 = (unsigned short*)ws;
    unsigned short* h1r1 = h1r0 + C * (size_t)TL * 256;
    unsigned short* o2r0 = (unsigned short*)(ws + C * 2097152ull);
    unsigned short* o2r1 = o2r0 + C * (size_t)TL * 128;
    float* sums = (float*)(ws + C * 3145728ull);

    int co[5]; co[0] = 0;
    for (int i = 1; i < nch; ++i) co[i] = co[i - 1] + cs[i - 1];

    for (int k = 0; k < nch + 2; ++k){
      const int a1 = (k < nch) ? cs[k] : 0;
      const int a2 = (k >= 1 && k < nch + 1) ? cs[k - 1] : 0;
      const int a3 = (k >= 2) ? cs[k - 2] : 0;
      const int nL1 = 2 * a1, nL2 = 2 * a2, nL3 = a3 / 2;
      mega_kernel<<<dim3(nL1 + nL2 + nL3), dim3(512), 0, stream>>>(
          nL1, nL2, nL3,
          (k < nch) ? co[k] : 0, (k >= 1 && k < nch + 1) ? co[k - 1] : 0,
          (k >= 2) ? co[k - 2] : 0,
          k & 1, (k + 1) & 1, k & 1,
          x, Wih1, Whh1, bih1, bhh1, Wih2, Whh2, bih2, bhh2,
          Wih3, Whh3, bih3, bhh3, h1r0, h1r1, o2r0, o2r1, sums);
    }
    head_kernel<<<dim3(256), dim3(64), 0, stream>>>(
        sums, hW1, hb1, hW2, hb2, hW3, hb3, (float*)d_out);
  }
}